// Round 11
// baseline (317.251 us; speedup 1.0000x reference)
//
#include <hip/hip_runtime.h>

// GroupedQueryAttention: B=2, S=2048, HIDDEN=2048, NH=16, NKV=4, HD=128, G=4
// R16: #pragma unroll 2 on the three main loops (attn, qkv, out). Buffer parity
//      (cur/p = t&1) becomes compile-time -> LICM hoists all XOR-swizzled LDS
//      addresses; kt/dt/buffer terms fold into DS immediate offsets. R15's VALU
//      census showed ~295 VALU insts/wave-iter in attn (~39% VALUBusy) dominated
//      by per-iter address recompute that runtime `cur` was blocking.
//      No other changes vs R15.

#define SEQ    2048
#define HIDDEN 2048

typedef __attribute__((ext_vector_type(8))) short v8s;   // 8 x bf16 (4 VGPRs)
typedef __attribute__((ext_vector_type(4))) float v4f;   // MFMA accumulator

#define MFMA16(a,b,c) __builtin_amdgcn_mfma_f32_16x16x32_bf16((a),(b),(c),0,0,0)

__device__ __forceinline__ ushort f2b(float f){
  unsigned u = __float_as_uint(f);
  u += 0x7fffu + ((u >> 16) & 1u);       // round-to-nearest-even
  return (ushort)(u >> 16);
}

__device__ __forceinline__ unsigned cvt_pk_bf16(float lo, float hi){
  unsigned r;
  asm("v_cvt_pk_bf16_f32 %0, %1, %2" : "=v"(r) : "v"(lo), "v"(hi));
  return r;
}

__device__ __forceinline__ void gload16(const void* g, void* l){
  __builtin_amdgcn_global_load_lds((const __attribute__((address_space(1))) void*)g,
                                   (__attribute__((address_space(3))) void*)l, 16, 0, 0);
}

// s_waitcnt immediates (gfx9): vmcnt[3:0]@0, expcnt@4, lgkmcnt@8, vmcnt[5:4]@14
#define WAIT_VM0   0x0F70   // vmcnt(0)
#define WAIT_VM2   0x0F72   // vmcnt(2)
#define WAIT_LGKM0 0xC07F   // lgkmcnt(0)

// ---------- fused preprocessing: fp32->bf16 conv + 4 weight transposes ----------
__global__ __launch_bounds__(256) void k_prep(
    const float* __restrict__ x,  const float* __restrict__ Wq,
    const float* __restrict__ Wk, const float* __restrict__ Wv,
    const float* __restrict__ Wo, ushort* __restrict__ xb,
    ushort* __restrict__ Wt, ushort* __restrict__ Wto){
  __shared__ float t[32][33];
  int id = blockIdx.x;
  if (id < 8192){
    int i = (id*256 + threadIdx.x)*4;
    float4 f = *(const float4*)(x + i);
    ushort4 u; u.x=f2b(f.x); u.y=f2b(f.y); u.z=f2b(f.z); u.w=f2b(f.w);
    *(ushort4*)(xb + i) = u;
    return;
  }
  id -= 8192;
  const float* in; ushort* out; int rows, cols, bx, by;
  if (id < 4096)      { in=Wq; out=Wt;           rows=2048; cols=2048; bx=id&63; by=id>>6; }
  else if (id < 5120) { id-=4096; in=Wk; out=Wt+4194304; rows=2048; cols=512; bx=id&15; by=id>>4; }
  else if (id < 6144) { id-=5120; in=Wv; out=Wt+5242880; rows=2048; cols=512; bx=id&15; by=id>>4; }
  else                { id-=6144; in=Wo; out=Wto;         rows=2048; cols=2048; bx=id&63; by=id>>6; }
  int tx = threadIdx.x & 31, ty = threadIdx.x >> 5;
  int c0 = bx*32, r0 = by*32;
#pragma unroll
  for (int i=0;i<4;i++) t[ty+i*8][tx] = in[(size_t)(r0+ty+i*8)*cols + c0+tx];
  __syncthreads();
#pragma unroll
  for (int i=0;i<4;i++) out[(size_t)(c0+ty+i*8)*rows + r0+tx] = f2b(t[tx][ty+i*8]);
}

// QKV GEMM: M=4096, N=3072(packed q|k|v), K=2048. BM=256 x BN=192, BK=64,
// grid dim3(16,16) = 256 blocks = 100% fill. 4-phase counted-vmcnt(2) skeleton;
// ALL t+1 staging at ph1 (3-phase min prefetch cover), A0(t+2) at ph4.
// Epilogue: q->qb, k->kb row-major; v -> vT (b,h,d,s) direct (ushort4 stores).
__global__ __launch_bounds__(512, 1) void k_gemm_qkv(
    const ushort* __restrict__ A, const ushort* __restrict__ Bt,
    const float* __restrict__ bq, const float* __restrict__ bk, const float* __restrict__ bv,
    ushort* __restrict__ qb, ushort* __restrict__ kb, ushort* __restrict__ vT){
  __shared__ ushort sA[2][2][128*64];   // [buf][half][16 chunks of 8 rows x 64k] 64KB
  __shared__ ushort sB[2][192*64];      // [buf][24 chunks of 8 rows x 64k] 48KB
  const int tid = threadIdx.x, lane = tid & 63, w = tid >> 6;
  const int wm = w >> 2, wn = w & 3, lm = lane & 15, quad = lane >> 4;
  const int l3 = lane >> 3, l7m = lm & 7;
  const int swz = ((lane & 7) ^ (l3 & 7)) * 8;
  const int rowB = blockIdx.y*256, colB = blockIdx.x*192;
  const ushort* Ag = A; const ushort* Bg = Bt;
  v4f acc[8][3] = {};

#define QSTG_A(t_, h_, buf_) { _Pragma("unroll") for (int i_=0;i_<2;i_++){             \
    int c_ = w*2 + i_;                                                                 \
    gload16(Ag + (size_t)(rowB + (h_)*128 + c_*8 + l3)*HIDDEN + (t_)*64 + swz,         \
            &sA[buf_][h_][c_*512 + lane*8]); } }
#define QSTG_B01(t_, buf_) { _Pragma("unroll") for (int i_=0;i_<2;i_++){               \
    int c_ = w*2 + i_;                                                                 \
    gload16(Bg + (size_t)(colB + c_*8 + l3)*HIDDEN + (t_)*64 + swz,                    \
            &sB[buf_][c_*512 + lane*8]); } }
#define QSTG_B2(t_, buf_) {                                                            \
    int c_ = 16 + w;                                                                   \
    gload16(Bg + (size_t)(colB + c_*8 + l3)*HIDDEN + (t_)*64 + swz,                    \
            &sB[buf_][c_*512 + lane*8]); }
#define QLDA(dst_, i_, ks_) dst_ = *(const v8s*)(&sA[p][wm][((i_)*16+lm)*64 + ((((ks_)*4+quad))^l7m)*8]);
#define QLDB(dst_, j_, ks_) dst_ = *(const v8s*)(&sB[p][(wn*48 + (j_)*16+lm)*64 + ((((ks_)*4+quad))^l7m)*8]);

  QSTG_A(0,0,0) QSTG_A(0,1,0) QSTG_B01(0,0) QSTG_B2(0,0) QSTG_A(1,0,1)
  __builtin_amdgcn_s_waitcnt(WAIT_VM2);
  __builtin_amdgcn_s_barrier(); __builtin_amdgcn_sched_barrier(0);
#pragma unroll 2
  for (int t = 0; t < 32; t++){
    const int p = t & 1, pn = p ^ 1;
    const int tn  = (t+1 < 32) ? t+1 : t;
    const int tnn = (t+2 < 32) ? t+2 : 31;
    v8s a0[4][2], a1[4][2], b01[2][2], b2[2];
    // ph1: read a0 + b01 regs; stage ALL of t+1 (A1, B01, B2 -> 5 loads)
#pragma unroll
    for (int i=0;i<4;i++){ QLDA(a0[i][0], i, 0) QLDA(a0[i][1], i, 1) }
#pragma unroll
    for (int j=0;j<2;j++){ QLDB(b01[j][0], j, 0) QLDB(b01[j][1], j, 1) }
    QSTG_A(tn, 1, pn) QSTG_B01(tn, pn) QSTG_B2(tn, pn)
    __builtin_amdgcn_s_barrier(); __builtin_amdgcn_sched_barrier(0);
    __builtin_amdgcn_s_waitcnt(WAIT_LGKM0); __builtin_amdgcn_sched_barrier(0);
    __builtin_amdgcn_s_setprio(1);
#pragma unroll
    for (int ks=0;ks<2;ks++)
#pragma unroll
      for (int i=0;i<4;i++)
#pragma unroll
        for (int j=0;j<2;j++) acc[i][j] = MFMA16(a0[i][ks], b01[j][ks], acc[i][j]);
    __builtin_amdgcn_s_setprio(0);
    __builtin_amdgcn_s_barrier(); __builtin_amdgcn_sched_barrier(0);
    // ph2: read b2 regs; no staging
    QLDB(b2[0], 2, 0) QLDB(b2[1], 2, 1)
    __builtin_amdgcn_s_barrier(); __builtin_amdgcn_sched_barrier(0);
    __builtin_amdgcn_s_waitcnt(WAIT_LGKM0); __builtin_amdgcn_sched_barrier(0);
    __builtin_amdgcn_s_setprio(1);
#pragma unroll
    for (int ks=0;ks<2;ks++)
#pragma unroll
      for (int i=0;i<4;i++) acc[i][2] = MFMA16(a0[i][ks], b2[ks], acc[i][2]);
    __builtin_amdgcn_s_setprio(0);
    __builtin_amdgcn_s_barrier(); __builtin_amdgcn_sched_barrier(0);
    // ph3: read a1 regs; no staging
#pragma unroll
    for (int i=0;i<4;i++){ QLDA(a1[i][0], i+4, 0) QLDA(a1[i][1], i+4, 1) }
    __builtin_amdgcn_s_barrier(); __builtin_amdgcn_sched_barrier(0);
    __builtin_amdgcn_s_waitcnt(WAIT_LGKM0); __builtin_amdgcn_sched_barrier(0);
    __builtin_amdgcn_s_setprio(1);
#pragma unroll
    for (int ks=0;ks<2;ks++)
#pragma unroll
      for (int i=0;i<4;i++)
#pragma unroll
        for (int j=0;j<2;j++) acc[i+4][j] = MFMA16(a1[i][ks], b01[j][ks], acc[i+4][j]);
    __builtin_amdgcn_s_setprio(0);
    __builtin_amdgcn_s_barrier(); __builtin_amdgcn_sched_barrier(0);
    // ph4: stage A0(t+2) into buf p (reads done by ph3); vm(2) leaves only A0(t+2)
    QSTG_A(tnn, 0, p)
    __builtin_amdgcn_s_waitcnt(WAIT_VM2); __builtin_amdgcn_sched_barrier(0);
    __builtin_amdgcn_s_barrier(); __builtin_amdgcn_sched_barrier(0);
    __builtin_amdgcn_s_setprio(1);
#pragma unroll
    for (int ks=0;ks<2;ks++)
#pragma unroll
      for (int i=0;i<4;i++) acc[i+4][2] = MFMA16(a1[i][ks], b2[ks], acc[i+4][2]);
    __builtin_amdgcn_s_setprio(0);
    __builtin_amdgcn_s_barrier(); __builtin_amdgcn_sched_barrier(0);
  }
#pragma unroll
  for (int i=0;i<8;i++)
#pragma unroll
  for (int j=0;j<3;j++){
    int col = colB + wn*48 + j*16 + lm;
    int row0 = rowB + wm*128 + i*16 + quad*4;
    if (col < 2048){
#pragma unroll
      for (int r=0;r<4;r++)
        qb[(size_t)(row0+r)*2048 + col] = f2b(acc[i][j][r] + bq[col]);
    } else if (col < 2560){
#pragma unroll
      for (int r=0;r<4;r++)
        kb[(size_t)(row0+r)*512 + (col-2048)] = f2b(acc[i][j][r] + bk[col-2048]);
    } else {
      // v -> vT (b,h,d,s) direct: 4 consecutive s at fixed d = one ushort4
      int vcol = col - 2560;                 // h*128 + d
      int b_ = row0 >> 11, s0 = row0 & 2047;
      float bvv = bv[vcol];
      ushort4 u;
      u.x = f2b(acc[i][j][0] + bvv);
      u.y = f2b(acc[i][j][1] + bvv);
      u.z = f2b(acc[i][j][2] + bvv);
      u.w = f2b(acc[i][j][3] + bvv);
      *(ushort4*)(vT + (size_t)(b_*4 + (vcol>>7))*262144 + (size_t)(vcol&127)*2048 + s0) = u;
    }
  }
#undef QSTG_A
#undef QSTG_B01
#undef QSTG_B2
#undef QLDA
#undef QLDB
}

// Output GEMM: M=4096, N=2048, K=2048. BM=128 x BN=256, grid dim3(8,32) = 256
// blocks = 100% fill. 2 phases/K-tile; both B halves of t+1 staged at ph1,
// A(t+2) at ph2. Counted vmcnt(2).
__global__ __launch_bounds__(512, 1) void k_gemm_out(
    const ushort* __restrict__ A, const ushort* __restrict__ Bt,
    const float* __restrict__ bo, float* __restrict__ out){
  __shared__ ushort sA[2][128*64], sB[2][2][128*64];
  const int tid = threadIdx.x, lane = tid & 63, w = tid >> 6;
  const int wm = w >> 2, wn = w & 3, lm = lane & 15, quad = lane >> 4;
  const int wh = wn >> 1, wl = wn & 1, l3 = lane >> 3, l7m = lm & 7;
  const int swz = ((lane & 7) ^ (l3 & 7)) * 8;
  const int rowB = blockIdx.y*128, colB = blockIdx.x*256;
  const ushort* Ag = A; const ushort* Bg = Bt;
  v4f acc[4][4] = {};

#define OSTG_A(t_, buf_) { _Pragma("unroll") for (int i_=0;i_<2;i_++){                 \
    int c_ = w*2 + i_;                                                                 \
    gload16(Ag + (size_t)(rowB + c_*8 + l3)*HIDDEN + (t_)*64 + swz,                    \
            &sA[buf_][c_*512 + lane*8]); } }
#define OSTG_B(t_, h_, buf_) { _Pragma("unroll") for (int i_=0;i_<2;i_++){             \
    int c_ = w*2 + i_;                                                                 \
    gload16(Bg + (size_t)(colB + (h_)*128 + c_*8 + l3)*HIDDEN + (t_)*64 + swz,         \
            &sB[buf_][h_][c_*512 + lane*8]); } }
#define OLDA(dst_, i_, ks_) dst_ = *(const v8s*)(&sA[p][(wm*64 + (i_)*16 + lm)*64 + ((((ks_)*4+quad))^l7m)*8]);
#define OLDB(dst_, j_, ks_) dst_ = *(const v8s*)(&sB[p][wh][(wl*64 + (j_)*16 + lm)*64 + ((((ks_)*4+quad))^l7m)*8]);

  OSTG_A(0,0) OSTG_B(0,0,0) OSTG_B(0,1,0) OSTG_A(1,1)
  __builtin_amdgcn_s_waitcnt(WAIT_VM2);
  __builtin_amdgcn_s_barrier(); __builtin_amdgcn_sched_barrier(0);
#pragma unroll 2
  for (int t = 0; t < 32; t++){
    const int p = t & 1, pn = p ^ 1;
    const int tn  = (t+1 < 32) ? t+1 : t;
    const int tnn = (t+2 < 32) ? t+2 : 31;
    v8s a[4][2], b0[2][2], b1[2][2];
    // ph1: read a + b01 regs; stage BOTH B halves of t+1
#pragma unroll
    for (int i=0;i<4;i++){ OLDA(a[i][0], i, 0) OLDA(a[i][1], i, 1) }
#pragma unroll
    for (int j=0;j<2;j++){ OLDB(b0[j][0], j, 0) OLDB(b0[j][1], j, 1) }
    OSTG_B(tn, 0, pn) OSTG_B(tn, 1, pn)
    __builtin_amdgcn_s_barrier(); __builtin_amdgcn_sched_barrier(0);
    __builtin_amdgcn_s_waitcnt(WAIT_LGKM0); __builtin_amdgcn_sched_barrier(0);
    __builtin_amdgcn_s_setprio(1);
#pragma unroll
    for (int ks=0;ks<2;ks++)
#pragma unroll
      for (int i=0;i<4;i++)
#pragma unroll
        for (int j=0;j<2;j++) acc[i][j] = MFMA16(a[i][ks], b0[j][ks], acc[i][j]);
    __builtin_amdgcn_s_setprio(0);
    __builtin_amdgcn_s_barrier(); __builtin_amdgcn_sched_barrier(0);
    // ph2: read b23 regs; stage A(t+2) into buf p (reads done since ph1); vm(2)
#pragma unroll
    for (int j=0;j<2;j++){ OLDB(b1[j][0], j+2, 0) OLDB(b1[j][1], j+2, 1) }
    OSTG_A(tnn, p)
    __builtin_amdgcn_s_waitcnt(WAIT_VM2); __builtin_amdgcn_sched_barrier(0);
    __builtin_amdgcn_s_barrier(); __builtin_amdgcn_sched_barrier(0);
    __builtin_amdgcn_s_waitcnt(WAIT_LGKM0); __builtin_amdgcn_sched_barrier(0);
    __builtin_amdgcn_s_setprio(1);
#pragma unroll
    for (int ks=0;ks<2;ks++)
#pragma unroll
      for (int i=0;i<4;i++)
#pragma unroll
        for (int j=0;j<2;j++) acc[i][j+2] = MFMA16(a[i][ks], b1[j][ks], acc[i][j+2]);
    __builtin_amdgcn_s_setprio(0);
    __builtin_amdgcn_s_barrier(); __builtin_amdgcn_sched_barrier(0);
  }
#pragma unroll
  for (int i=0;i<4;i++)
#pragma unroll
  for (int j=0;j<4;j++){
    int col = colB + wn*64 + j*16 + lm;
#pragma unroll
    for (int r=0;r<4;r++){
      int row = rowB + wm*64 + i*16 + quad*4 + r;
      out[(size_t)row*2048 + col] = acc[i][j][r] + bo[col];
    }
  }
#undef OSTG_A
#undef OSTG_B
#undef OLDA
#undef OLDB
}

// ---------- Flash attention (R8): 2 blocks/CU, 8 waves x 16 q-rows ----------
__global__ __launch_bounds__(512, 2) void k_attn(
    const ushort* __restrict__ qb, const ushort* __restrict__ kb,
    const ushort* __restrict__ vT, ushort* __restrict__ Ob){
  __shared__ ushort sK[2][64*128];   // swizzled: row=key (128 ushort), slot = wd^(key&15)
  __shared__ ushort sV[2][128*64];   // swizzled: row=d   (64 ushort),  slot = wd^(d&7)
  __shared__ ushort sP[8][1024];     // per-wave P: [kc2][512]
  const int tid = threadIdx.x, lane = tid & 63, w = tid >> 6;
  const int lm = lane & 15, quad = lane >> 4, q8 = quad*8;
  const int pair = blockIdx.x & 7;          // hkv + 4*b  -> XCD-partitions K/V
  const int hkv = pair & 3, b = pair >> 2;
  const int qt = (blockIdx.x >> 3) & 15, g = blockIdx.x >> 7;
  const int head = hkv*4 + g;
  const float C = 0.08838834764831845f * 1.4426950408889634f;  // SCALE * log2(e)

  const ushort* kbb = kb + (size_t)b*SEQ*512 + hkv*128;
  const ushort* vbb = vT + (size_t)(b*4+hkv)*128*SEQ;

  const int kk = lane >> 4, ksw = lane & 15;      // K: 4 keys/chunk
  const int dd = lane >> 3, vsw = lane & 7;       // V: 8 d-rows/chunk

#define STAGE_K(t, buf) { _Pragma("unroll") for (int i=0;i<2;i++){                     \
    int c = w*2 + i; int key = c*4 + kk; int wd = ksw ^ (key & 15);                    \
    gload16(kbb + (size_t)((t)*64 + key)*512 + wd*8, &sK[buf][c*512 + lane*8]); } }
#define STAGE_V(t, buf) { _Pragma("unroll") for (int i=0;i<2;i++){                     \
    int c = w*2 + i; int drow = c*8 + dd; int wd = vsw ^ dd;                           \
    gload16(vbb + (size_t)drow*SEQ + (t)*64 + wd*8, &sV[buf][c*512 + lane*8]); } }

  // Q fragments (B-operand): qrow = qt*128 + w*16 + lm
  v8s qf[4];
#pragma unroll
  for (int ks=0; ks<4; ks++)
    qf[ks] = *(const v8s*)(qb + (size_t)(b*SEQ + qt*128 + w*16 + lm)*HIDDEN
                              + head*128 + ks*32 + q8);

  v4f o[8] = {};
  float lreg = 0.f;

  STAGE_K(0, 0)
  STAGE_V(0, 0)
  __builtin_amdgcn_s_waitcnt(WAIT_VM0);
  __syncthreads();

#pragma unroll 2
  for (int t=0; t<32; t++){
    const int cur = t & 1;
    if (t < 31) STAGE_K(t+1, cur^1)

    v4f sacc[4] = {};
#pragma unroll
    for (int ks=0; ks<4; ks++){
      v8s kf[4];
#pragma unroll
      for (int kt=0; kt<4; kt++)
        kf[kt] = *(const v8s*)(&sK[cur][(kt*16+lm)*128 + ((ks*4+quad)^lm)*8]);
      __builtin_amdgcn_s_setprio(1);
#pragma unroll
      for (int kt=0; kt<4; kt++)
        sacc[kt] = MFMA16(kf[kt], qf[ks], sacc[kt]);
      __builtin_amdgcn_s_setprio(0);
    }

    {
      float rs = 0.f;
#pragma unroll
      for (int kt=0; kt<4; kt++){
        float p0 = __builtin_amdgcn_exp2f(sacc[kt][0]*C);
        float p1 = __builtin_amdgcn_exp2f(sacc[kt][1]*C);
        float p2 = __builtin_amdgcn_exp2f(sacc[kt][2]*C);
        float p3 = __builtin_amdgcn_exp2f(sacc[kt][3]*C);
        rs += (p0+p1)+(p2+p3);
        uint2 pk;
        pk.x = cvt_pk_bf16(p0, p1);
        pk.y = cvt_pk_bf16(p2, p3);
        int kc = kt >> 1;
        int dl = ((kt&1)*2 + (quad>>1))*16 + lm;
        *(uint2*)(&sP[w][kc*512 + dl*8 + (quad&1)*4]) = pk;
      }
      lreg += rs;
    }

    __builtin_amdgcn_s_waitcnt(WAIT_VM0);   // own K(t+1) + V(t) DMA done
    __syncthreads();
    if (t < 31) STAGE_V(t+1, cur^1)

    __builtin_amdgcn_s_waitcnt(WAIT_LGKM0); // own P writes visible
    v8s pa[2];
#pragma unroll
    for (int kc=0; kc<2; kc++)
      pa[kc] = *(const v8s*)(&sP[w][kc*512 + lane*8]);
#pragma unroll
    for (int kc=0; kc<2; kc++){
      v8s vf[8];
#pragma unroll
      for (int dt=0; dt<8; dt++)
        vf[dt] = *(const v8s*)(&sV[cur][(dt*16+lm)*64 + ((kc*4+quad)^(lm&7))*8]);
      __builtin_amdgcn_s_setprio(1);
#pragma unroll
      for (int dt=0; dt<8; dt++)
        o[dt] = MFMA16(pa[kc], vf[dt], o[dt]);
      __builtin_amdgcn_s_setprio(0);
    }
  }

  {
    float lv = lreg;
    lv += __shfl_xor(lv, 16);
    lv += __shfl_xor(lv, 32);
    float inv[4];
#pragma unroll
    for (int r=0;r<4;r++) inv[r] = 1.0f / __shfl(lv, (lane & 48) + quad*4 + r);
#pragma unroll
    for (int dt=0; dt<8; dt++)
#pragma unroll
      for (int r=0;r<4;r++){
        int row = b*SEQ + qt*128 + w*16 + quad*4 + r;
        int col = head*128 + dt*16 + lm;
        Ob[(size_t)row*HIDDEN + col] = f2b(o[dt][r]*inv[r]);
      }
  }
#undef STAGE_K
#undef STAGE_V
}

extern "C" void kernel_launch(void* const* d_in, const int* in_sizes, int n_in,
                              void* d_out, int out_size, void* d_ws, size_t ws_size,
                              hipStream_t stream){
  const float* x  = (const float*)d_in[0];
  const float* Wq = (const float*)d_in[1];
  const float* bq = (const float*)d_in[2];
  const float* Wk = (const float*)d_in[3];
  const float* bk = (const float*)d_in[4];
  const float* Wv = (const float*)d_in[5];
  const float* bv = (const float*)d_in[6];
  const float* Wo = (const float*)d_in[7];
  const float* bo = (const float*)d_in[8];
  float* out = (float*)d_out;

  // workspace layout (bf16 elems)
  ushort* xb  = (ushort*)d_ws;        // 4096x2048
  ushort* Wt  = xb  + 8388608;        // 3072x2048  (Wq^T | Wk^T | Wv^T)
  ushort* Wto = Wt  + 6291456;        // 2048x2048  (Wo^T)
  ushort* qb  = Wto + 4194304;        // 4096x2048
  ushort* kb  = qb  + 8388608;        // 4096x512
  ushort* vT  = kb  + 2097152;        // (b,h,d,s) 2x4x128x2048
  ushort* Ob  = vT  + 2097152;        // 4096x2048

  k_prep<<<18432, 256, 0, stream>>>(x, Wq, Wk, Wv, Wo, xb, Wt, Wto);
  k_gemm_qkv<<<dim3(16,16), 512, 0, stream>>>(xb, Wt, bq, bk, bv, qb, kb, vT);
  k_attn<<<512, 512, 0, stream>>>(qb, kb, vT, Ob);
  k_gemm_out<<<dim3(8,32), 512, 0, stream>>>(Ob, Wto, bo, out);
}

// Round 12
// 305.337 us; speedup vs baseline: 1.0390x; 1.0390x over previous
//
#include <hip/hip_runtime.h>

// GroupedQueryAttention: B=2, S=2048, HIDDEN=2048, NH=16, NKV=4, HD=128, G=4
// R17: split verdict from R16's unroll-2 experiment -- KEEP unroll 2 on both
//      GEMM main loops (combined ~4.5us gain: address LICM, barrier-lockstep
//      structure tolerates big bodies), REVERT it on attn (cost 11us: occupancy
//      36.6->21, the 2-blocks/CU cross-block overlap broke; both pipes' util
//      dropped). Otherwise identical to R15.

#define SEQ    2048
#define HIDDEN 2048

typedef __attribute__((ext_vector_type(8))) short v8s;   // 8 x bf16 (4 VGPRs)
typedef __attribute__((ext_vector_type(4))) float v4f;   // MFMA accumulator

#define MFMA16(a,b,c) __builtin_amdgcn_mfma_f32_16x16x32_bf16((a),(b),(c),0,0,0)

__device__ __forceinline__ ushort f2b(float f){
  unsigned u = __float_as_uint(f);
  u += 0x7fffu + ((u >> 16) & 1u);       // round-to-nearest-even
  return (ushort)(u >> 16);
}

__device__ __forceinline__ unsigned cvt_pk_bf16(float lo, float hi){
  unsigned r;
  asm("v_cvt_pk_bf16_f32 %0, %1, %2" : "=v"(r) : "v"(lo), "v"(hi));
  return r;
}

__device__ __forceinline__ void gload16(const void* g, void* l){
  __builtin_amdgcn_global_load_lds((const __attribute__((address_space(1))) void*)g,
                                   (__attribute__((address_space(3))) void*)l, 16, 0, 0);
}

// s_waitcnt immediates (gfx9): vmcnt[3:0]@0, expcnt@4, lgkmcnt@8, vmcnt[5:4]@14
#define WAIT_VM0   0x0F70   // vmcnt(0)
#define WAIT_VM2   0x0F72   // vmcnt(2)
#define WAIT_LGKM0 0xC07F   // lgkmcnt(0)

// ---------- fused preprocessing: fp32->bf16 conv + 4 weight transposes ----------
__global__ __launch_bounds__(256) void k_prep(
    const float* __restrict__ x,  const float* __restrict__ Wq,
    const float* __restrict__ Wk, const float* __restrict__ Wv,
    const float* __restrict__ Wo, ushort* __restrict__ xb,
    ushort* __restrict__ Wt, ushort* __restrict__ Wto){
  __shared__ float t[32][33];
  int id = blockIdx.x;
  if (id < 8192){
    int i = (id*256 + threadIdx.x)*4;
    float4 f = *(const float4*)(x + i);
    ushort4 u; u.x=f2b(f.x); u.y=f2b(f.y); u.z=f2b(f.z); u.w=f2b(f.w);
    *(ushort4*)(xb + i) = u;
    return;
  }
  id -= 8192;
  const float* in; ushort* out; int rows, cols, bx, by;
  if (id < 4096)      { in=Wq; out=Wt;           rows=2048; cols=2048; bx=id&63; by=id>>6; }
  else if (id < 5120) { id-=4096; in=Wk; out=Wt+4194304; rows=2048; cols=512; bx=id&15; by=id>>4; }
  else if (id < 6144) { id-=5120; in=Wv; out=Wt+5242880; rows=2048; cols=512; bx=id&15; by=id>>4; }
  else                { id-=6144; in=Wo; out=Wto;         rows=2048; cols=2048; bx=id&63; by=id>>6; }
  int tx = threadIdx.x & 31, ty = threadIdx.x >> 5;
  int c0 = bx*32, r0 = by*32;
#pragma unroll
  for (int i=0;i<4;i++) t[ty+i*8][tx] = in[(size_t)(r0+ty+i*8)*cols + c0+tx];
  __syncthreads();
#pragma unroll
  for (int i=0;i<4;i++) out[(size_t)(c0+ty+i*8)*rows + r0+tx] = f2b(t[tx][ty+i*8]);
}

// QKV GEMM: M=4096, N=3072(packed q|k|v), K=2048. BM=256 x BN=192, BK=64,
// grid dim3(16,16) = 256 blocks = 100% fill. 4-phase counted-vmcnt(2) skeleton;
// ALL t+1 staging at ph1 (3-phase min prefetch cover), A0(t+2) at ph4. unroll 2.
// Epilogue: q->qb, k->kb row-major; v -> vT (b,h,d,s) direct (ushort4 stores).
__global__ __launch_bounds__(512, 1) void k_gemm_qkv(
    const ushort* __restrict__ A, const ushort* __restrict__ Bt,
    const float* __restrict__ bq, const float* __restrict__ bk, const float* __restrict__ bv,
    ushort* __restrict__ qb, ushort* __restrict__ kb, ushort* __restrict__ vT){
  __shared__ ushort sA[2][2][128*64];   // [buf][half][16 chunks of 8 rows x 64k] 64KB
  __shared__ ushort sB[2][192*64];      // [buf][24 chunks of 8 rows x 64k] 48KB
  const int tid = threadIdx.x, lane = tid & 63, w = tid >> 6;
  const int wm = w >> 2, wn = w & 3, lm = lane & 15, quad = lane >> 4;
  const int l3 = lane >> 3, l7m = lm & 7;
  const int swz = ((lane & 7) ^ (l3 & 7)) * 8;
  const int rowB = blockIdx.y*256, colB = blockIdx.x*192;
  const ushort* Ag = A; const ushort* Bg = Bt;
  v4f acc[8][3] = {};

#define QSTG_A(t_, h_, buf_) { _Pragma("unroll") for (int i_=0;i_<2;i_++){             \
    int c_ = w*2 + i_;                                                                 \
    gload16(Ag + (size_t)(rowB + (h_)*128 + c_*8 + l3)*HIDDEN + (t_)*64 + swz,         \
            &sA[buf_][h_][c_*512 + lane*8]); } }
#define QSTG_B01(t_, buf_) { _Pragma("unroll") for (int i_=0;i_<2;i_++){               \
    int c_ = w*2 + i_;                                                                 \
    gload16(Bg + (size_t)(colB + c_*8 + l3)*HIDDEN + (t_)*64 + swz,                    \
            &sB[buf_][c_*512 + lane*8]); } }
#define QSTG_B2(t_, buf_) {                                                            \
    int c_ = 16 + w;                                                                   \
    gload16(Bg + (size_t)(colB + c_*8 + l3)*HIDDEN + (t_)*64 + swz,                    \
            &sB[buf_][c_*512 + lane*8]); }
#define QLDA(dst_, i_, ks_) dst_ = *(const v8s*)(&sA[p][wm][((i_)*16+lm)*64 + ((((ks_)*4+quad))^l7m)*8]);
#define QLDB(dst_, j_, ks_) dst_ = *(const v8s*)(&sB[p][(wn*48 + (j_)*16+lm)*64 + ((((ks_)*4+quad))^l7m)*8]);

  QSTG_A(0,0,0) QSTG_A(0,1,0) QSTG_B01(0,0) QSTG_B2(0,0) QSTG_A(1,0,1)
  __builtin_amdgcn_s_waitcnt(WAIT_VM2);
  __builtin_amdgcn_s_barrier(); __builtin_amdgcn_sched_barrier(0);
#pragma unroll 2
  for (int t = 0; t < 32; t++){
    const int p = t & 1, pn = p ^ 1;
    const int tn  = (t+1 < 32) ? t+1 : t;
    const int tnn = (t+2 < 32) ? t+2 : 31;
    v8s a0[4][2], a1[4][2], b01[2][2], b2[2];
    // ph1: read a0 + b01 regs; stage ALL of t+1 (A1, B01, B2 -> 5 loads)
#pragma unroll
    for (int i=0;i<4;i++){ QLDA(a0[i][0], i, 0) QLDA(a0[i][1], i, 1) }
#pragma unroll
    for (int j=0;j<2;j++){ QLDB(b01[j][0], j, 0) QLDB(b01[j][1], j, 1) }
    QSTG_A(tn, 1, pn) QSTG_B01(tn, pn) QSTG_B2(tn, pn)
    __builtin_amdgcn_s_barrier(); __builtin_amdgcn_sched_barrier(0);
    __builtin_amdgcn_s_waitcnt(WAIT_LGKM0); __builtin_amdgcn_sched_barrier(0);
    __builtin_amdgcn_s_setprio(1);
#pragma unroll
    for (int ks=0;ks<2;ks++)
#pragma unroll
      for (int i=0;i<4;i++)
#pragma unroll
        for (int j=0;j<2;j++) acc[i][j] = MFMA16(a0[i][ks], b01[j][ks], acc[i][j]);
    __builtin_amdgcn_s_setprio(0);
    __builtin_amdgcn_s_barrier(); __builtin_amdgcn_sched_barrier(0);
    // ph2: read b2 regs; no staging
    QLDB(b2[0], 2, 0) QLDB(b2[1], 2, 1)
    __builtin_amdgcn_s_barrier(); __builtin_amdgcn_sched_barrier(0);
    __builtin_amdgcn_s_waitcnt(WAIT_LGKM0); __builtin_amdgcn_sched_barrier(0);
    __builtin_amdgcn_s_setprio(1);
#pragma unroll
    for (int ks=0;ks<2;ks++)
#pragma unroll
      for (int i=0;i<4;i++) acc[i][2] = MFMA16(a0[i][ks], b2[ks], acc[i][2]);
    __builtin_amdgcn_s_setprio(0);
    __builtin_amdgcn_s_barrier(); __builtin_amdgcn_sched_barrier(0);
    // ph3: read a1 regs; no staging
#pragma unroll
    for (int i=0;i<4;i++){ QLDA(a1[i][0], i+4, 0) QLDA(a1[i][1], i+4, 1) }
    __builtin_amdgcn_s_barrier(); __builtin_amdgcn_sched_barrier(0);
    __builtin_amdgcn_s_waitcnt(WAIT_LGKM0); __builtin_amdgcn_sched_barrier(0);
    __builtin_amdgcn_s_setprio(1);
#pragma unroll
    for (int ks=0;ks<2;ks++)
#pragma unroll
      for (int i=0;i<4;i++)
#pragma unroll
        for (int j=0;j<2;j++) acc[i+4][j] = MFMA16(a1[i][ks], b01[j][ks], acc[i+4][j]);
    __builtin_amdgcn_s_setprio(0);
    __builtin_amdgcn_s_barrier(); __builtin_amdgcn_sched_barrier(0);
    // ph4: stage A0(t+2) into buf p (reads done by ph3); vm(2) leaves only A0(t+2)
    QSTG_A(tnn, 0, p)
    __builtin_amdgcn_s_waitcnt(WAIT_VM2); __builtin_amdgcn_sched_barrier(0);
    __builtin_amdgcn_s_barrier(); __builtin_amdgcn_sched_barrier(0);
    __builtin_amdgcn_s_setprio(1);
#pragma unroll
    for (int ks=0;ks<2;ks++)
#pragma unroll
      for (int i=0;i<4;i++) acc[i+4][2] = MFMA16(a1[i][ks], b2[ks], acc[i+4][2]);
    __builtin_amdgcn_s_setprio(0);
    __builtin_amdgcn_s_barrier(); __builtin_amdgcn_sched_barrier(0);
  }
#pragma unroll
  for (int i=0;i<8;i++)
#pragma unroll
  for (int j=0;j<3;j++){
    int col = colB + wn*48 + j*16 + lm;
    int row0 = rowB + wm*128 + i*16 + quad*4;
    if (col < 2048){
#pragma unroll
      for (int r=0;r<4;r++)
        qb[(size_t)(row0+r)*2048 + col] = f2b(acc[i][j][r] + bq[col]);
    } else if (col < 2560){
#pragma unroll
      for (int r=0;r<4;r++)
        kb[(size_t)(row0+r)*512 + (col-2048)] = f2b(acc[i][j][r] + bk[col-2048]);
    } else {
      // v -> vT (b,h,d,s) direct: 4 consecutive s at fixed d = one ushort4
      int vcol = col - 2560;                 // h*128 + d
      int b_ = row0 >> 11, s0 = row0 & 2047;
      float bvv = bv[vcol];
      ushort4 u;
      u.x = f2b(acc[i][j][0] + bvv);
      u.y = f2b(acc[i][j][1] + bvv);
      u.z = f2b(acc[i][j][2] + bvv);
      u.w = f2b(acc[i][j][3] + bvv);
      *(ushort4*)(vT + (size_t)(b_*4 + (vcol>>7))*262144 + (size_t)(vcol&127)*2048 + s0) = u;
    }
  }
#undef QSTG_A
#undef QSTG_B01
#undef QSTG_B2
#undef QLDA
#undef QLDB
}

// Output GEMM: M=4096, N=2048, K=2048. BM=128 x BN=256, grid dim3(8,32) = 256
// blocks = 100% fill. 2 phases/K-tile; both B halves of t+1 staged at ph1,
// A(t+2) at ph2. Counted vmcnt(2). unroll 2.
__global__ __launch_bounds__(512, 1) void k_gemm_out(
    const ushort* __restrict__ A, const ushort* __restrict__ Bt,
    const float* __restrict__ bo, float* __restrict__ out){
  __shared__ ushort sA[2][128*64], sB[2][2][128*64];
  const int tid = threadIdx.x, lane = tid & 63, w = tid >> 6;
  const int wm = w >> 2, wn = w & 3, lm = lane & 15, quad = lane >> 4;
  const int wh = wn >> 1, wl = wn & 1, l3 = lane >> 3, l7m = lm & 7;
  const int swz = ((lane & 7) ^ (l3 & 7)) * 8;
  const int rowB = blockIdx.y*128, colB = blockIdx.x*256;
  const ushort* Ag = A; const ushort* Bg = Bt;
  v4f acc[4][4] = {};

#define OSTG_A(t_, buf_) { _Pragma("unroll") for (int i_=0;i_<2;i_++){                 \
    int c_ = w*2 + i_;                                                                 \
    gload16(Ag + (size_t)(rowB + c_*8 + l3)*HIDDEN + (t_)*64 + swz,                    \
            &sA[buf_][c_*512 + lane*8]); } }
#define OSTG_B(t_, h_, buf_) { _Pragma("unroll") for (int i_=0;i_<2;i_++){             \
    int c_ = w*2 + i_;                                                                 \
    gload16(Bg + (size_t)(colB + (h_)*128 + c_*8 + l3)*HIDDEN + (t_)*64 + swz,         \
            &sB[buf_][h_][c_*512 + lane*8]); } }
#define OLDA(dst_, i_, ks_) dst_ = *(const v8s*)(&sA[p][(wm*64 + (i_)*16 + lm)*64 + ((((ks_)*4+quad))^l7m)*8]);
#define OLDB(dst_, j_, ks_) dst_ = *(const v8s*)(&sB[p][wh][(wl*64 + (j_)*16 + lm)*64 + ((((ks_)*4+quad))^l7m)*8]);

  OSTG_A(0,0) OSTG_B(0,0,0) OSTG_B(0,1,0) OSTG_A(1,1)
  __builtin_amdgcn_s_waitcnt(WAIT_VM2);
  __builtin_amdgcn_s_barrier(); __builtin_amdgcn_sched_barrier(0);
#pragma unroll 2
  for (int t = 0; t < 32; t++){
    const int p = t & 1, pn = p ^ 1;
    const int tn  = (t+1 < 32) ? t+1 : t;
    const int tnn = (t+2 < 32) ? t+2 : 31;
    v8s a[4][2], b0[2][2], b1[2][2];
    // ph1: read a + b01 regs; stage BOTH B halves of t+1
#pragma unroll
    for (int i=0;i<4;i++){ OLDA(a[i][0], i, 0) OLDA(a[i][1], i, 1) }
#pragma unroll
    for (int j=0;j<2;j++){ OLDB(b0[j][0], j, 0) OLDB(b0[j][1], j, 1) }
    OSTG_B(tn, 0, pn) OSTG_B(tn, 1, pn)
    __builtin_amdgcn_s_barrier(); __builtin_amdgcn_sched_barrier(0);
    __builtin_amdgcn_s_waitcnt(WAIT_LGKM0); __builtin_amdgcn_sched_barrier(0);
    __builtin_amdgcn_s_setprio(1);
#pragma unroll
    for (int ks=0;ks<2;ks++)
#pragma unroll
      for (int i=0;i<4;i++)
#pragma unroll
        for (int j=0;j<2;j++) acc[i][j] = MFMA16(a[i][ks], b0[j][ks], acc[i][j]);
    __builtin_amdgcn_s_setprio(0);
    __builtin_amdgcn_s_barrier(); __builtin_amdgcn_sched_barrier(0);
    // ph2: read b23 regs; stage A(t+2) into buf p (reads done since ph1); vm(2)
#pragma unroll
    for (int j=0;j<2;j++){ OLDB(b1[j][0], j+2, 0) OLDB(b1[j][1], j+2, 1) }
    OSTG_A(tnn, p)
    __builtin_amdgcn_s_waitcnt(WAIT_VM2); __builtin_amdgcn_sched_barrier(0);
    __builtin_amdgcn_s_barrier(); __builtin_amdgcn_sched_barrier(0);
    __builtin_amdgcn_s_waitcnt(WAIT_LGKM0); __builtin_amdgcn_sched_barrier(0);
    __builtin_amdgcn_s_setprio(1);
#pragma unroll
    for (int ks=0;ks<2;ks++)
#pragma unroll
      for (int i=0;i<4;i++)
#pragma unroll
        for (int j=0;j<2;j++) acc[i][j+2] = MFMA16(a[i][ks], b1[j][ks], acc[i][j+2]);
    __builtin_amdgcn_s_setprio(0);
    __builtin_amdgcn_s_barrier(); __builtin_amdgcn_sched_barrier(0);
  }
#pragma unroll
  for (int i=0;i<4;i++)
#pragma unroll
  for (int j=0;j<4;j++){
    int col = colB + wn*64 + j*16 + lm;
#pragma unroll
    for (int r=0;r<4;r++){
      int row = rowB + wm*64 + i*16 + quad*4 + r;
      out[(size_t)row*2048 + col] = acc[i][j][r] + bo[col];
    }
  }
#undef OSTG_A
#undef OSTG_B
#undef OLDA
#undef OLDB
}

// ---------- Flash attention (R8/R15): 2 blocks/CU, 8 waves x 16 q-rows ----------
// NO unroll on the t-loop: R16 showed unroll-2 here costs 11us (occupancy
// 36.6->21, cross-block overlap broken) despite saving VALU.
__global__ __launch_bounds__(512, 2) void k_attn(
    const ushort* __restrict__ qb, const ushort* __restrict__ kb,
    const ushort* __restrict__ vT, ushort* __restrict__ Ob){
  __shared__ ushort sK[2][64*128];   // swizzled: row=key (128 ushort), slot = wd^(key&15)
  __shared__ ushort sV[2][128*64];   // swizzled: row=d   (64 ushort),  slot = wd^(d&7)
  __shared__ ushort sP[8][1024];     // per-wave P: [kc2][512]
  const int tid = threadIdx.x, lane = tid & 63, w = tid >> 6;
  const int lm = lane & 15, quad = lane >> 4, q8 = quad*8;
  const int pair = blockIdx.x & 7;          // hkv + 4*b  -> XCD-partitions K/V
  const int hkv = pair & 3, b = pair >> 2;
  const int qt = (blockIdx.x >> 3) & 15, g = blockIdx.x >> 7;
  const int head = hkv*4 + g;
  const float C = 0.08838834764831845f * 1.4426950408889634f;  // SCALE * log2(e)

  const ushort* kbb = kb + (size_t)b*SEQ*512 + hkv*128;
  const ushort* vbb = vT + (size_t)(b*4+hkv)*128*SEQ;

  const int kk = lane >> 4, ksw = lane & 15;      // K: 4 keys/chunk
  const int dd = lane >> 3, vsw = lane & 7;       // V: 8 d-rows/chunk

#define STAGE_K(t, buf) { _Pragma("unroll") for (int i=0;i<2;i++){                     \
    int c = w*2 + i; int key = c*4 + kk; int wd = ksw ^ (key & 15);                    \
    gload16(kbb + (size_t)((t)*64 + key)*512 + wd*8, &sK[buf][c*512 + lane*8]); } }
#define STAGE_V(t, buf) { _Pragma("unroll") for (int i=0;i<2;i++){                     \
    int c = w*2 + i; int drow = c*8 + dd; int wd = vsw ^ dd;                           \
    gload16(vbb + (size_t)drow*SEQ + (t)*64 + wd*8, &sV[buf][c*512 + lane*8]); } }

  // Q fragments (B-operand): qrow = qt*128 + w*16 + lm
  v8s qf[4];
#pragma unroll
  for (int ks=0; ks<4; ks++)
    qf[ks] = *(const v8s*)(qb + (size_t)(b*SEQ + qt*128 + w*16 + lm)*HIDDEN
                              + head*128 + ks*32 + q8);

  v4f o[8] = {};
  float lreg = 0.f;

  STAGE_K(0, 0)
  STAGE_V(0, 0)
  __builtin_amdgcn_s_waitcnt(WAIT_VM0);
  __syncthreads();

  for (int t=0; t<32; t++){
    const int cur = t & 1;
    if (t < 31) STAGE_K(t+1, cur^1)

    v4f sacc[4] = {};
#pragma unroll
    for (int ks=0; ks<4; ks++){
      v8s kf[4];
#pragma unroll
      for (int kt=0; kt<4; kt++)
        kf[kt] = *(const v8s*)(&sK[cur][(kt*16+lm)*128 + ((ks*4+quad)^lm)*8]);
      __builtin_amdgcn_s_setprio(1);
#pragma unroll
      for (int kt=0; kt<4; kt++)
        sacc[kt] = MFMA16(kf[kt], qf[ks], sacc[kt]);
      __builtin_amdgcn_s_setprio(0);
    }

    {
      float rs = 0.f;
#pragma unroll
      for (int kt=0; kt<4; kt++){
        float p0 = __builtin_amdgcn_exp2f(sacc[kt][0]*C);
        float p1 = __builtin_amdgcn_exp2f(sacc[kt][1]*C);
        float p2 = __builtin_amdgcn_exp2f(sacc[kt][2]*C);
        float p3 = __builtin_amdgcn_exp2f(sacc[kt][3]*C);
        rs += (p0+p1)+(p2+p3);
        uint2 pk;
        pk.x = cvt_pk_bf16(p0, p1);
        pk.y = cvt_pk_bf16(p2, p3);
        int kc = kt >> 1;
        int dl = ((kt&1)*2 + (quad>>1))*16 + lm;
        *(uint2*)(&sP[w][kc*512 + dl*8 + (quad&1)*4]) = pk;
      }
      lreg += rs;
    }

    __builtin_amdgcn_s_waitcnt(WAIT_VM0);   // own K(t+1) + V(t) DMA done
    __syncthreads();
    if (t < 31) STAGE_V(t+1, cur^1)

    __builtin_amdgcn_s_waitcnt(WAIT_LGKM0); // own P writes visible
    v8s pa[2];
#pragma unroll
    for (int kc=0; kc<2; kc++)
      pa[kc] = *(const v8s*)(&sP[w][kc*512 + lane*8]);
#pragma unroll
    for (int kc=0; kc<2; kc++){
      v8s vf[8];
#pragma unroll
      for (int dt=0; dt<8; dt++)
        vf[dt] = *(const v8s*)(&sV[cur][(dt*16+lm)*64 + ((kc*4+quad)^(lm&7))*8]);
      __builtin_amdgcn_s_setprio(1);
#pragma unroll
      for (int dt=0; dt<8; dt++)
        o[dt] = MFMA16(pa[kc], vf[dt], o[dt]);
      __builtin_amdgcn_s_setprio(0);
    }
  }

  {
    float lv = lreg;
    lv += __shfl_xor(lv, 16);
    lv += __shfl_xor(lv, 32);
    float inv[4];
#pragma unroll
    for (int r=0;r<4;r++) inv[r] = 1.0f / __shfl(lv, (lane & 48) + quad*4 + r);
#pragma unroll
    for (int dt=0; dt<8; dt++)
#pragma unroll
      for (int r=0;r<4;r++){
        int row = b*SEQ + qt*128 + w*16 + quad*4 + r;
        int col = head*128 + dt*16 + lm;
        Ob[(size_t)row*HIDDEN + col] = f2b(o[dt][r]*inv[r]);
      }
  }
#undef STAGE_K
#undef STAGE_V
}

extern "C" void kernel_launch(void* const* d_in, const int* in_sizes, int n_in,
                              void* d_out, int out_size, void* d_ws, size_t ws_size,
                              hipStream_t stream){
  const float* x  = (const float*)d_in[0];
  const float* Wq = (const float*)d_in[1];
  const float* bq = (const float*)d_in[2];
  const float* Wk = (const float*)d_in[3];
  const float* bk = (const float*)d_in[4];
  const float* Wv = (const float*)d_in[5];
  const float* bv = (const float*)d_in[6];
  const float* Wo = (const float*)d_in[7];
  const float* bo = (const float*)d_in[8];
  float* out = (float*)d_out;

  // workspace layout (bf16 elems)
  ushort* xb  = (ushort*)d_ws;        // 4096x2048
  ushort* Wt  = xb  + 8388608;        // 3072x2048  (Wq^T | Wk^T | Wv^T)
  ushort* Wto = Wt  + 6291456;        // 2048x2048  (Wo^T)
  ushort* qb  = Wto + 4194304;        // 4096x2048
  ushort* kb  = qb  + 8388608;        // 4096x512
  ushort* vT  = kb  + 2097152;        // (b,h,d,s) 2x4x128x2048
  ushort* Ob  = vT  + 2097152;        // 4096x2048

  k_prep<<<18432, 256, 0, stream>>>(x, Wq, Wk, Wv, Wo, xb, Wt, Wto);
  k_gemm_qkv<<<dim3(16,16), 512, 0, stream>>>(xb, Wt, bq, bk, bv, qb, kb, vT);
  k_attn<<<512, 512, 0, stream>>>(qb, kb, vT, Ob);
  k_gemm_out<<<dim3(8,32), 512, 0, stream>>>(Ob, Wto, bo, out);
}